// Round 9
// baseline (395.130 us; speedup 1.0000x reference)
//
#include <hip/hip_runtime.h>
#include <hip/hip_bf16.h>

#define NN 2048
#define NE 65536
#define NG 32
#define CIN 128
#define CED 32
#define CLAT 64
#define CFA 16
#define CNB 5
#define NL 5

#define OFF_AT (NN * CLAT)
#define OFF_B  (NN * CLAT + NN * CFA)

typedef __attribute__((ext_vector_type(8))) short bf16x8;
typedef __attribute__((ext_vector_type(4))) float f32x4;

__device__ __forceinline__ float silu_f(float v) { return v / (1.0f + __expf(-v)); }
__device__ __forceinline__ short f2bs(float v) {
    __hip_bfloat16 h = __float2bfloat16(v);
    return *reinterpret_cast<short*>(&h);
}
__device__ __forceinline__ float bs2f(short s) {
    return __bfloat162float(*reinterpret_cast<__hip_bfloat16*>(&s));
}
__device__ __forceinline__ unsigned pack2(float a, float b) {
    return ((unsigned)(unsigned short)f2bs(b) << 16) | (unsigned short)f2bs(a);
}
__device__ __forceinline__ unsigned addpack(unsigned ua, unsigned va) {
    float a0 = bs2f((short)(ua & 0xffff)), a1 = bs2f((short)(ua >> 16));
    float b0 = bs2f((short)(va & 0xffff)), b1 = bs2f((short)(va >> 16));
    return pack2(a0 + b0, a1 + b1);
}
// device-coherent 64-bit load (bypasses L1/L2, reads LLC) — used by vscatter so it needs no
// cache-wide acquire fence when consuming same-dispatch producer data.
__device__ __forceinline__ unsigned long long ld_sc64(const unsigned long long* p) {
    return __hip_atomic_load(p, __ATOMIC_RELAXED, __HIP_MEMORY_SCOPE_AGENT);
}

struct KArgs {
    const float *x, *t, *z;
    const int *jj, *ii;           // edge_index rows 0 (j) and 1 (i)
    const float *ea;
    const int *batch, *beg;
    const float *Wt_a, *bt_a, *Wt_b, *bt_b, *W_atom, *b_atom, *W_bond, *b_bond;
    const float *W_lat, *b_lat, *W_at, *b_at, *W_bt, *b_bt;
    const float *Wmsg, *bmsg, *Wnode, *bnode, *Wedge, *bedge;
    const float *Wsh, *bsh, *Wbm, *bbm, *Wbl, *bbl, *Wal, *bal;
    float *s, *e;
    float *agg;                   // partial sums: [NN][4][CIN] f32, slot-indexed, no atomics
    int *cnt, *pflag, *eflag, *cnt2, *nflag, *rowpos, *rowpos2, *rowstart, *invp, *i_s, *j_s;
    int *j_s2, *tgt2;             // j-sorted: j value / i-sorted target position
    short *s2, *U, *V, *P, *Q;    // bf16 storage
    int *map;
    short *Wpn, *Wpsh, *Wpal, *Wpbm, *Wproj, *W3m, *We3;
    short *uvt0, *pqt0;           // double-buffered V/Q scatter targets (bufN = base + N*stride)
    float *out;
};

// ---------------- phase: pack weights (strided) ------------------------------------------------
__device__ __forceinline__ void phase_pack(const KArgs& a, int start, int stride)
{
    for (int idx = start; idx < 6 * 4 * 20 * 64 * 8; idx += stride) {
        int j = idx & 7, t0 = idx >> 3, lane = t0 & 63, tt = t0 >> 6;
        int kq = (lane >> 4) * 8 + j, n16 = lane & 15;
        if (idx < NL * 8 * 8 * 64 * 8) { // Wnode K=256 N=128
            int nt = tt & 7, kt = (tt >> 3) & 7, l = tt >> 6;
            a.Wpn[idx] = f2bs(a.Wnode[((size_t)l * 256 + kt * 32 + kq) * CIN + nt * 16 + n16]);
        }
        if (idx < 4 * 8 * 64 * 8) { // Wsh K=128 N=128
            int nt = tt & 7, kt = tt >> 3;
            a.Wpsh[idx] = f2bs(a.Wsh[(size_t)(kt * 32 + kq) * CIN + nt * 16 + n16]);
        }
        if (idx < 4 * 5 * 64 * 8) { // Wal K=128 N=80
            int nt = tt % 5, kt = tt / 5;
            a.Wpal[idx] = f2bs(a.Wal[(size_t)(kt * 32 + kq) * 80 + nt * 16 + n16]);
        }
        if (idx < 8 * 64 * 8) { // Wbm K=32 N=128
            int nt = tt & 7;
            a.Wpbm[idx] = f2bs(a.Wbm[(size_t)kq * CIN + nt * 16 + n16]);
        }
        { // Wproj: 6 slots, K=128, N=320 (bound == loop bound)
            int nt = tt % 20; int t2 = tt / 20; int kt = t2 & 3; int slot = t2 >> 2;
            int k = kt * 32 + kq;
            float v;
            if (nt < 16) {
                int msgl = slot % 5;
                int srcK = (nt < 8) ? k : 128 + k;
                int col = (nt & 7) * 16 + n16;
                v = a.Wmsg[((size_t)msgl * 288 + srcK) * CIN + col];
            } else {
                int edgel = (slot == 0) ? 0 : slot - 1;
                int srcK = (nt < 18) ? k : 128 + k;
                int col = (nt & 1) * 16 + n16;
                v = a.Wedge[((size_t)edgel * 288 + srcK) * CED + col];
            }
            a.Wproj[idx] = f2bs(v);
        }
        if (idx < NL * 8 * 64 * 8) { // W3m: Wmsg rows 256..287, K=32 N=128
            int nt = tt & 7, l = tt >> 3;
            a.W3m[idx] = f2bs(a.Wmsg[((size_t)l * 288 + 256 + kq) * CIN + nt * 16 + n16]);
        }
        if (idx < NL * 2 * 64 * 8) { // We3: Wedge rows 256..287, K=32 N=32
            int nt = tt & 1, l = tt >> 1;
            a.We3[idx] = f2bs(a.Wedge[((size_t)l * 288 + 256 + kq) * CED + nt * 16 + n16]);
        }
    }
}

// ---------------- phase: init s (16 nodes per tile) --------------------------------------------
__device__ __forceinline__ void phase_init_s(const KArgs& a, char* smem, int tile, int tid)
{
    float* xs  = (float*)smem;            // 16*16
    float* zs  = (float*)(smem + 1024);   // 16*64
    float* tmp = (float*)(smem + 5120);   // 16*128
    float* tv  = (float*)(smem + 13312);  // 16
    int nb0 = tile * 16;
    int c = tid & 127, h = tid >> 7;
    if (tid < 16 * CFA / 4) ((float4*)xs)[tid] = ((const float4*)a.x)[nb0 * (CFA / 4) + tid];
    if (tid < 16 * CLAT / 4) ((float4*)zs)[tid] = ((const float4*)a.z)[nb0 * (CLAT / 4) + tid];
    if (tid < 16) tv[tid] = a.t[a.batch[nb0 + tid]];
    __syncthreads();
    float wta = a.Wt_a[c], base0 = a.b_atom[c] + a.bt_a[c];
    float acc[8];
#pragma unroll
    for (int q = 0; q < 8; q++) acc[q] = base0 + tv[h * 8 + q] * wta;
    for (int k = 0; k < CFA; k++) {
        float w = a.W_atom[k * CIN + c];
#pragma unroll
        for (int q = 0; q < 8; q++) acc[q] += xs[(h * 8 + q) * CFA + k] * w;
    }
#pragma unroll
    for (int q = 0; q < 8; q++) tmp[(h * 8 + q) * CIN + c] = acc[q];
    __syncthreads();
    float base1 = a.b_at[c] + a.b_lat[c];
    float acc2[8];
#pragma unroll
    for (int q = 0; q < 8; q++) acc2[q] = base1;
    for (int k4 = 0; k4 < CIN / 4; k4++) {
        float w0 = a.W_at[(4 * k4 + 0) * CIN + c], w1 = a.W_at[(4 * k4 + 1) * CIN + c];
        float w2 = a.W_at[(4 * k4 + 2) * CIN + c], w3 = a.W_at[(4 * k4 + 3) * CIN + c];
#pragma unroll
        for (int q = 0; q < 8; q++) {
            float4 f = *(const float4*)&tmp[(h * 8 + q) * CIN + 4 * k4];
            acc2[q] += f.x * w0 + f.y * w1 + f.z * w2 + f.w * w3;
        }
    }
    for (int k4 = 0; k4 < CLAT / 4; k4++) {
        float w0 = a.W_lat[(4 * k4 + 0) * CIN + c], w1 = a.W_lat[(4 * k4 + 1) * CIN + c];
        float w2 = a.W_lat[(4 * k4 + 2) * CIN + c], w3 = a.W_lat[(4 * k4 + 3) * CIN + c];
#pragma unroll
        for (int q = 0; q < 8; q++) {
            float4 f = *(const float4*)&zs[(h * 8 + q) * CLAT + 4 * k4];
            acc2[q] += f.x * w0 + f.y * w1 + f.z * w2 + f.w * w3;
        }
    }
#pragma unroll
    for (int q = 0; q < 8; q++) {
        int nd = nb0 + h * 8 + q;
        a.s[(size_t)nd * CIN + c] = acc2[q];
    }
}

// ---------------- phase: init e tile (64 edges), sorted-order write ----------------------------
__device__ __forceinline__ void phase_init_e(const KArgs& a, char* smem, int tb, int tid)
{
    float* eas   = (float*)smem;            // 320
    float* tv    = (float*)(smem + 1280);   // 64
    int*   sp    = (int*)(smem + 1536);     // 64
    float* tmp   = (float*)(smem + 1792);   // 64*33
    float* wbt   = (float*)(smem + 10240);  // 1024
    float* wbond = (float*)(smem + 14336);  // 160
    float* cb    = (float*)(smem + 14976);
    float* wtb   = (float*)(smem + 15104);
    float* bbt2  = (float*)(smem + 15232);
    int k0 = tb * 64;
    for (int idx = tid; idx < 320; idx += 256) eas[idx] = a.ea[(size_t)k0 * 5 + idx];
    if (tid < 64) { tv[tid] = a.t[a.beg[k0 + tid]]; sp[tid] = a.invp[k0 + tid]; }
    for (int idx = tid; idx < 1024; idx += 256) wbt[idx] = a.W_bt[idx];
    if (tid < 160) wbond[tid] = a.W_bond[tid];
    if (tid < 32) { cb[tid] = a.b_bond[tid] + a.bt_b[tid]; wtb[tid] = a.Wt_b[tid]; bbt2[tid] = a.b_bt[tid]; }
    __syncthreads();
    int ch = tid & 31, eg = tid >> 5;
#pragma unroll
    for (int q = 0; q < 8; q++) {
        int le = eg * 8 + q;
        float acc = cb[ch] + tv[le] * wtb[ch];
#pragma unroll
        for (int bb = 0; bb < CNB; bb++) acc += eas[le * 5 + bb] * wbond[bb * 32 + ch];
        tmp[le * 33 + ch] = acc;
    }
    __syncthreads();
#pragma unroll
    for (int q = 0; q < 8; q++) {
        int le = eg * 8 + q;
        float acc2 = bbt2[ch];
        for (int d = 0; d < 32; d++) acc2 += tmp[le * 33 + d] * wbt[d * 32 + ch];
        size_t ix = (size_t)sp[le] * CED + ch;
        a.e[ix] = acc2;
        if (ch == 0) {
            int k = k0 + le;
            atomicMax(&a.map[(size_t)a.jj[k] * NN + a.ii[k]], k); // numpy last-write-wins
        }
    }
}

// ---------------- phase: V/Q scatter (64 j-sorted edges) ---------------------------------------
// Reads V[j]/Q[j] rows (2-3 distinct j per tile, via sc loads: LLC-fresh, no fence) and
// scatter-writes them into i-sorted layout (uvt/pqt) — scattered WRITES don't stall.
__device__ __forceinline__ void phase_vscatter(const KArgs& a, char* smem, int tb, int tid,
                                               short* uvt, short* pqt, const int* nflag, int gen)
{
    int* js = (int*)smem;          // 64
    int* tg = (int*)(smem + 256);  // 64
    int e0 = tb * 64;
    if (tid < 64) js[tid] = a.j_s2[e0 + tid];
    else if (tid < 128) tg[tid - 64] = a.tgt2[e0 + tid - 64];
    __syncthreads();
    if (nflag) {
        if (tid == 0) {
            int t0 = js[0] >> 4, t1 = js[63] >> 4;   // j sorted -> contiguous node-tile range
            for (int t = t0; t <= t1; t++)
                while (__hip_atomic_load(&nflag[t * 16], __ATOMIC_RELAXED, __HIP_MEMORY_SCOPE_AGENT) < gen)
                    __builtin_amdgcn_s_sleep(2);
        }
        __syncthreads();
        asm volatile("" ::: "memory");
    }
    unsigned long long vv[8];
#pragma unroll
    for (int k2 = 0; k2 < 8; k2++) {               // V rows: 64 x 32 u64 chunks
        int idx = tid + k2 * 256;
        int kl = idx >> 5, c = idx & 31;
        vv[k2] = ld_sc64((const unsigned long long*)a.V + (size_t)js[kl] * 32 + c);
    }
    unsigned long long qq[2];
#pragma unroll
    for (int k2 = 0; k2 < 2; k2++) {               // Q rows: 64 x 8 u64 chunks
        int idx = tid + k2 * 256;
        int kl = idx >> 3, c = idx & 7;
        qq[k2] = ld_sc64((const unsigned long long*)a.Q + (size_t)js[kl] * 8 + c);
    }
#pragma unroll
    for (int k2 = 0; k2 < 8; k2++) {
        int idx = tid + k2 * 256;
        int kl = idx >> 5, c = idx & 31;
        ((unsigned long long*)uvt)[(size_t)tg[kl] * 32 + c] = vv[k2];
    }
#pragma unroll
    for (int k2 = 0; k2 < 2; k2++) {
        int idx = tid + k2 * 256;
        int kl = idx >> 3, c = idx & 7;
        ((unsigned long long*)pqt)[(size_t)tg[kl] * 8 + c] = qq[k2];
    }
}

// ---------------- phase: node update + projections (16 nodes/tile) -----------------------------
__device__ __forceinline__ void phase_node2(
    const KArgs& a, char* smem, int tile, int tid, bool DO_NODE, bool DO_POST,
    bool LOAD_S, bool STORE_S,
    const short* Wpn_l, const float* bnode_l, const short* Wproj_slot, float (*s_reg)[4],
    const int* eflag, int gen, int* nflag, int ngen)
{
    short* feat  = (short*)smem;            // 16*264 (aliased as feat_s2 in post phase)
    short* feat2 = (short*)(smem + 8448);   // 16*136
    int nb0 = tile * 16;
    int lane = tid & 63, w = tid >> 6;
    int quad = lane >> 4, n16 = lane & 15;

    if (DO_NODE) {
        if (eflag) {
            if (tid == 0) {
                int r0 = a.rowstart[nb0];
                int ed = (nb0 + 16 < NN) ? a.rowstart[nb0 + 16] : NE;
                if (ed > r0) {
                    int t1 = (ed - 1) >> 6;
                    for (int t = r0 >> 6; t <= t1; t++)
                        while (__hip_atomic_load(&eflag[t], __ATOMIC_RELAXED, __HIP_MEMORY_SCOPE_AGENT) < gen)
                            __builtin_amdgcn_s_sleep(2);
                }
            }
            __syncthreads();
            __threadfence();   // acquire: invalidate stale L1/L2 before reading remote agg
        }
#pragma unroll
        for (int n2 = 0; n2 < 2; n2++) {
            int col = (w * 2 + n2) * 16 + n16;
#pragma unroll
            for (int r = 0; r < 4; r++) {
                int row = quad * 4 + r;
                if (LOAD_S) s_reg[n2][r] = a.s[(size_t)(nb0 + row) * CIN + col];
                feat[row * 264 + col] = f2bs(s_reg[n2][r]);
            }
        }
#pragma unroll
        for (int k2 = 0; k2 < 2; k2++) {
            int idx = tid + k2 * 256;            // 16*32 float4 lanes
            int kl = idx >> 5, c = idx & 31;
            size_t base = (size_t)(nb0 + kl) * 128 + c;   // float4 units; slot stride 32
            float4 p0 = ((const float4*)a.agg)[base];
            float4 p1 = ((const float4*)a.agg)[base + 32];
            float4 p2 = ((const float4*)a.agg)[base + 64];
            float4 p3 = ((const float4*)a.agg)[base + 96];
            float4 v; v.x = p0.x + p1.x + p2.x + p3.x; v.y = p0.y + p1.y + p2.y + p3.y;
            v.z = p0.z + p1.z + p2.z + p3.z; v.w = p0.w + p1.w + p2.w + p3.w;
            uint2 p; p.x = pack2(v.x, v.y); p.y = pack2(v.z, v.w);
            *(uint2*)&feat[kl * 264 + 128 + 4 * c] = p;
        }
        __syncthreads();
        f32x4 acc[2];
        acc[0] = (f32x4){0.f, 0.f, 0.f, 0.f};
        acc[1] = (f32x4){0.f, 0.f, 0.f, 0.f};
        const short* fbase = feat + n16 * 264 + quad * 8;
#pragma unroll
        for (int kt = 0; kt < 8; kt++) {
            bf16x8 av = *(const bf16x8*)(fbase + kt * 32);
#pragma unroll
            for (int n2 = 0; n2 < 2; n2++) {
                int nt = w * 2 + n2;
                bf16x8 b = *(const bf16x8*)(Wpn_l + ((size_t)(kt * 8 + nt) * 64 + lane) * 8);
                acc[n2] = __builtin_amdgcn_mfma_f32_16x16x32_bf16(av, b, acc[n2], 0, 0, 0);
            }
        }
#pragma unroll
        for (int n2 = 0; n2 < 2; n2++) {
            int col = (w * 2 + n2) * 16 + n16;
            float bb = bnode_l[col];
#pragma unroll
            for (int r = 0; r < 4; r++) {
                int row = quad * 4 + r;
                float v = s_reg[n2][r] + silu_f(acc[n2][r] + bb);
                s_reg[n2][r] = v;
                if (STORE_S) a.s[(size_t)(nb0 + row) * CIN + col] = v;
                feat2[row * 136 + col] = f2bs(v);
            }
        }
        __syncthreads();
    } else {
        int kl = tid >> 4, c = tid & 15;
        const float4* sp4 = (const float4*)&a.s[(size_t)(nb0 + kl) * CIN + c * 8];
        float4 v0 = sp4[0], v1 = sp4[1];
        uint4 p; p.x = pack2(v0.x, v0.y); p.y = pack2(v0.z, v0.w);
        p.z = pack2(v1.x, v1.y); p.w = pack2(v1.z, v1.w);
        *(uint4*)&feat2[kl * 136 + c * 8] = p;
        __syncthreads();
    }

    // projections: [U|V|P|Q] = s_new @ Wproj (K=128, N=320); wave w -> nt 5w..5w+4
    {
        f32x4 accp[5];
#pragma unroll
        for (int t2 = 0; t2 < 5; t2++) accp[t2] = (f32x4){0.f, 0.f, 0.f, 0.f};
        const short* abase = feat2 + n16 * 136 + quad * 8;
#pragma unroll
        for (int kt = 0; kt < 4; kt++) {
            bf16x8 av = *(const bf16x8*)(abase + kt * 32);
#pragma unroll
            for (int n5 = 0; n5 < 5; n5++) {
                int nt = w * 5 + n5;
                bf16x8 b = *(const bf16x8*)(Wproj_slot + ((size_t)(kt * 20 + nt) * 64 + lane) * 8);
                accp[n5] = __builtin_amdgcn_mfma_f32_16x16x32_bf16(av, b, accp[n5], 0, 0, 0);
            }
        }
#pragma unroll
        for (int n5 = 0; n5 < 5; n5++) {
            int nt = w * 5 + n5;
#pragma unroll
            for (int r = 0; r < 4; r++) {
                int node = tile * 16 + quad * 4 + r;
                short bv = f2bs(accp[n5][r]);
                if (nt < 8)       a.U[(size_t)node * CIN + nt * 16 + n16] = bv;
                else if (nt < 16) a.V[(size_t)node * CIN + (nt - 8) * 16 + n16] = bv;
                else if (nt < 18) a.P[(size_t)node * CED + (nt - 16) * 16 + n16] = bv;
                else              a.Q[(size_t)node * CED + (nt - 18) * 16 + n16] = bv;
            }
        }
    }

    // signal vscatter consumers (same dispatch): U/V/P/Q stores drained by syncthreads,
    // leader wbl2 pushes them to LLC, then per-node-tile flag store.
    if (nflag) {
        __syncthreads();
        if (tid == 0) {
            __threadfence();
            __hip_atomic_store(&nflag[tile * 16], ngen, __ATOMIC_RELAXED, __HIP_MEMORY_SCOPE_AGENT);
        }
    }

    if (DO_POST) {
        short* feat_s2 = feat;
        const short* fbase = feat2 + n16 * 136 + quad * 8;
        f32x4 acc[2];
        acc[0] = (f32x4){0.f, 0.f, 0.f, 0.f};
        acc[1] = (f32x4){0.f, 0.f, 0.f, 0.f};
#pragma unroll
        for (int kt = 0; kt < 4; kt++) {
            bf16x8 av = *(const bf16x8*)(fbase + kt * 32);
#pragma unroll
            for (int n2 = 0; n2 < 2; n2++) {
                int nt = w * 2 + n2;
                bf16x8 b = *(const bf16x8*)(a.Wpsh + ((size_t)(kt * 8 + nt) * 64 + lane) * 8);
                acc[n2] = __builtin_amdgcn_mfma_f32_16x16x32_bf16(av, b, acc[n2], 0, 0, 0);
            }
        }
#pragma unroll
        for (int n2 = 0; n2 < 2; n2++) {
            int col = (w * 2 + n2) * 16 + n16;
            float bb = a.bsh[col];
#pragma unroll
            for (int r = 0; r < 4; r++) {
                int row = quad * 4 + r;
                float v = silu_f(acc[n2][r] + bb);
                short bv = f2bs(v);
                a.s2[(size_t)(nb0 + row) * CIN + col] = bv;
                feat_s2[row * 136 + col] = bv;
            }
        }
        __syncthreads();
        const short* abase2 = feat_s2 + n16 * 136 + quad * 8;
        f32x4 acca[2];
        acca[0] = (f32x4){0.f, 0.f, 0.f, 0.f};
        acca[1] = (f32x4){0.f, 0.f, 0.f, 0.f};
        int nAl = (w == 0) ? 2 : 1;
        int ntl[2] = {w, 4};
#pragma unroll
        for (int kt = 0; kt < 4; kt++) {
            bf16x8 av = *(const bf16x8*)(abase2 + kt * 32);
#pragma unroll
            for (int q = 0; q < 2; q++) {
                if (q < nAl) {
                    bf16x8 b = *(const bf16x8*)(a.Wpal + ((size_t)(kt * 5 + ntl[q]) * 64 + lane) * 8);
                    acca[q] = __builtin_amdgcn_mfma_f32_16x16x32_bf16(av, b, acca[q], 0, 0, 0);
                }
            }
        }
#pragma unroll
        for (int q = 0; q < 2; q++) {
            if (q < nAl) {
                int col = ntl[q] * 16 + n16;
                float bb = a.bal[col];
#pragma unroll
                for (int r = 0; r < 4; r++) {
                    int node = nb0 + quad * 4 + r;
                    float v = acca[q][r] + bb;
                    if (col < CFA) a.out[OFF_AT + node * CFA + col] = v;
                    else           a.out[(size_t)node * CLAT + (col - CFA)] = v;
                }
            }
        }
    }
}

// ---------------- phase: per-edge tile (64 sorted edges) ---------------------------------------
// uvt/pqt non-null: V/Q come COALESCED from the scatter buffers (same values, same rounding).
// LDS: feat_e 5120 | uv_bf 17408 | pq_bf 5120 | sii 256 | sjj 256 = 28160 B
__device__ __forceinline__ void phase_em2(
    const KArgs& a, char* smem, int tb, int tid, bool DO_EDGE, bool DO_MSG, bool LOAD_E, bool WRITE_E,
    const short* We3p, const float* bedge_l, const short* W3mp, const float* bmsg_l,
    float (*e_reg)[4], int* eflag, int gen, const short* uvt, const short* pqt)
{
    short* feat_e = (short*)smem;             // 64*40 bf16
    short* uv_bf  = (short*)(smem + 5120);    // 64*136 bf16 (U[i]+V[j]; then m values)
    short* pq_bf  = (short*)(smem + 22528);   // 64*40 bf16 (P[i]+Q[j])
    int*   sii    = (int*)(smem + 27648);     // 64
    int*   sjj    = (int*)(smem + 27904);     // 64
    int e0 = tb * 64;
    int lane = tid & 63, w = tid >> 6;
    int quad = lane >> 4, n16 = lane & 15;
    if (tid < 64) sii[tid] = a.i_s[e0 + tid];
    else if (tid < 128) sjj[tid - 64] = a.j_s[e0 + tid - 64];
    __syncthreads();
#pragma unroll
    for (int nt = 0; nt < 2; nt++) {
        int ch = nt * 16 + n16;
#pragma unroll
        for (int r = 0; r < 4; r++) {
            int el = w * 16 + quad * 4 + r;
            if (LOAD_E) e_reg[nt][r] = a.e[(size_t)(e0 + el) * CED + ch];
            feat_e[el * 40 + ch] = f2bs(e_reg[nt][r]);
        }
    }
    if (DO_EDGE) {
        uint2 pa[2], qb[2];
#pragma unroll
        for (int k2 = 0; k2 < 2; k2++) {
            int idx = tid + k2 * 256;
            int kl = idx >> 3, c = idx & 7;
            pa[k2] = ((const uint2*)a.P)[(size_t)sii[kl] * 8 + c];
            qb[k2] = pqt ? ((const uint2*)pqt)[(size_t)(e0 + kl) * 8 + c]
                         : ((const uint2*)a.Q)[(size_t)sjj[kl] * 8 + c];
        }
#pragma unroll
        for (int k2 = 0; k2 < 2; k2++) {
            int idx = tid + k2 * 256;
            int kl = idx >> 3, c = idx & 7;
            uint2 o; o.x = addpack(pa[k2].x, qb[k2].x); o.y = addpack(pa[k2].y, qb[k2].y);
            *(uint2*)&pq_bf[kl * 40 + 4 * c] = o;
        }
    }
    if (DO_MSG) {
        uint4 ua[4], va[4];
#pragma unroll
        for (int k2 = 0; k2 < 4; k2++) {
            int idx = tid + k2 * 256;
            int kl = idx >> 4, c = idx & 15;
            ua[k2] = ((const uint4*)a.U)[(size_t)sii[kl] * 16 + c];
            va[k2] = uvt ? ((const uint4*)uvt)[(size_t)(e0 + kl) * 16 + c]
                         : ((const uint4*)a.V)[(size_t)sjj[kl] * 16 + c];
        }
#pragma unroll
        for (int k2 = 0; k2 < 4; k2++) {
            int idx = tid + k2 * 256;
            int kl = idx >> 4, c = idx & 15;
            uint4 o; o.x = addpack(ua[k2].x, va[k2].x); o.y = addpack(ua[k2].y, va[k2].y);
            o.z = addpack(ua[k2].z, va[k2].z); o.w = addpack(ua[k2].w, va[k2].w);
            *(uint4*)&uv_bf[kl * 136 + c * 8] = o;
        }
    }
    __syncthreads();
    const short* abase = feat_e + (w * 16 + n16) * 40 + quad * 8;
    bf16x8 av = *(const bf16x8*)abase;

    if (DO_EDGE) {
        f32x4 acc_e[2];
        acc_e[0] = (f32x4){0.f, 0.f, 0.f, 0.f};
        acc_e[1] = (f32x4){0.f, 0.f, 0.f, 0.f};
#pragma unroll
        for (int nt = 0; nt < 2; nt++) {
            bf16x8 b = *(const bf16x8*)(We3p + ((size_t)(nt * 64 + lane)) * 8);
            acc_e[nt] = __builtin_amdgcn_mfma_f32_16x16x32_bf16(av, b, acc_e[nt], 0, 0, 0);
        }
#pragma unroll
        for (int nt = 0; nt < 2; nt++) {
            int ch = nt * 16 + n16;
            float bb = bedge_l[ch];
#pragma unroll
            for (int r = 0; r < 4; r++) {
                int el = w * 16 + quad * 4 + r;
                float v = e_reg[nt][r] + silu_f(acc_e[nt][r] + bb + bs2f(pq_bf[el * 40 + ch]));
                e_reg[nt][r] = v;
                feat_e[el * 40 + ch] = f2bs(v);
                if (WRITE_E) a.e[(size_t)(e0 + el) * CED + ch] = v;
            }
        }
        av = *(const bf16x8*)abase; // re-read own-wave patched row
    }

    if (DO_MSG) {
        f32x4 acc_m[8];
#pragma unroll
        for (int t2 = 0; t2 < 8; t2++) acc_m[t2] = (f32x4){0.f, 0.f, 0.f, 0.f};
#pragma unroll
        for (int nt = 0; nt < 8; nt++) {
            bf16x8 b = *(const bf16x8*)(W3mp + ((size_t)(nt * 64 + lane)) * 8);
            acc_m[nt] = __builtin_amdgcn_mfma_f32_16x16x32_bf16(av, b, acc_m[nt], 0, 0, 0);
        }
#pragma unroll
        for (int nt = 0; nt < 8; nt++) {
            int ch = nt * 16 + n16;
            float bb = bmsg_l[ch];
#pragma unroll
            for (int r = 0; r < 4; r++) {
                int el = w * 16 + quad * 4 + r;
                int lix = el * 136 + ch;
                float m = silu_f(acc_m[nt][r] + bb + bs2f(uv_bf[lix]));
                uv_bf[lix] = f2bs(m);
            }
        }
        __syncthreads();
        if (tid < 128) { // group-reduce by sorted target -> per-tile partial rows
            int c = tid;
            float run = 0.f;
            int cur = sii[0];
            for (int r = 0; r < 64; r++) {
                int tg = sii[r];
                if (tg != cur) {
                    int slot = tb - (a.rowstart[cur] >> 6); slot = (slot > 3) ? 3 : slot;
                    a.agg[((size_t)cur * 4 + slot) * CIN + c] = run;
                    run = 0.f; cur = tg;
                }
                run += bs2f(uv_bf[r * 136 + c]);
            }
            int slot = tb - (a.rowstart[cur] >> 6); slot = (slot > 3) ? 3 : slot;
            a.agg[((size_t)cur * 4 + slot) * CIN + c] = run;
        }
        if (eflag) {
            __syncthreads();
            if (tid == 0) {
                __threadfence();   // release before flag store
                __hip_atomic_store(&eflag[tb], gen, __ATOMIC_RELAXED, __HIP_MEMORY_SCOPE_AGENT);
            }
        }
    }
}

// ---------------- phase: post edge tile (64 edges, original order); bf16 staging ---------------
__device__ __forceinline__ void phase_post_edge(const KArgs& a, char* smem, int tb, int tid)
{
    short* esym  = (short*)smem;             // 64*40
    short* sbias = (short*)(smem + 5120);    // [64][132] bf16; aliased as fshT [128][66] bf16
    int* sii = (int*)(smem + 22016);
    int* sjj = (int*)(smem + 22272);
    int* skf = (int*)(smem + 22528);
    int* skb = (int*)(smem + 22784);
    int e0 = tb * 64;
    if (tid < 64) sii[tid] = a.ii[e0 + tid];
    else if (tid < 128) sjj[tid - 64] = a.jj[e0 + tid - 64];
    __syncthreads();
    if (tid < 64) skf[tid] = a.invp[a.map[(size_t)sjj[tid] * NN + sii[tid]]];
    else if (tid < 128) {
        int m = a.map[(size_t)sii[tid - 64] * NN + sjj[tid - 64]];
        skb[tid - 64] = (m >= 0) ? a.invp[m] : -1;
    }
    __syncthreads();
    {
        float4 av2[2], bv2[2];
#pragma unroll
        for (int k2 = 0; k2 < 2; k2++) {
            int idx = tid + k2 * 256;
            int kl = idx >> 3, c = idx & 7;
            av2[k2] = ((const float4*)a.e)[(size_t)skf[kl] * 8 + c];
            int kb = skb[kl];
            bv2[k2] = (float4){0.f, 0.f, 0.f, 0.f};
            if (kb >= 0) bv2[k2] = ((const float4*)a.e)[(size_t)kb * 8 + c];
        }
#pragma unroll
        for (int k2 = 0; k2 < 2; k2++) {
            int idx = tid + k2 * 256;
            int kl = idx >> 3, c = idx & 7;
            uint2 p; p.x = pack2(0.5f * (av2[k2].x + bv2[k2].x), 0.5f * (av2[k2].y + bv2[k2].y));
            p.y = pack2(0.5f * (av2[k2].z + bv2[k2].z), 0.5f * (av2[k2].w + bv2[k2].w));
            *(uint2*)&esym[kl * 40 + 4 * c] = p;
        }
    }
#pragma unroll
    for (int half = 0; half < 2; half++) {
        uint2 av4[4], bv4[4];
#pragma unroll
        for (int k2 = 0; k2 < 4; k2++) {
            int idx = tid + (half * 4 + k2) * 256;
            int kl = idx >> 5, c = idx & 31;
            av4[k2] = ((const uint2*)a.s2)[(size_t)sii[kl] * 32 + c];
            bv4[k2] = ((const uint2*)a.s2)[(size_t)sjj[kl] * 32 + c];
        }
#pragma unroll
        for (int k2 = 0; k2 < 4; k2++) {
            int idx = tid + (half * 4 + k2) * 256;
            int kl = idx >> 5, c = idx & 31;
            uint2 o; o.x = addpack(av4[k2].x, bv4[k2].x); o.y = addpack(av4[k2].y, bv4[k2].y);
            *(uint2*)&sbias[kl * 132 + 4 * c] = o;
        }
    }
    __syncthreads();
    int lane = tid & 63, w = tid >> 6;
    int quad = lane >> 4, n16 = lane & 15;
    bf16x8 av = *(const bf16x8*)(esym + (w * 16 + n16) * 40 + quad * 8);
    f32x4 acc[8];
#pragma unroll
    for (int nt = 0; nt < 8; nt++) {
        bf16x8 b = *(const bf16x8*)(a.Wpbm + ((size_t)nt * 64 + lane) * 8);
        f32x4 zero = {0.f, 0.f, 0.f, 0.f};
        acc[nt] = __builtin_amdgcn_mfma_f32_16x16x32_bf16(av, b, zero, 0, 0, 0);
    }
    float f[8][4];
#pragma unroll
    for (int nt = 0; nt < 8; nt++) {
        int col = nt * 16 + n16;
        float bb = a.bbm[col];
#pragma unroll
        for (int r = 0; r < 4; r++) {
            int row = w * 16 + quad * 4 + r;
            f[nt][r] = silu_f(acc[nt][r] + bb + bs2f(sbias[row * 132 + col]));
        }
    }
    __syncthreads();
    short* fshT = sbias; // [128][66] bf16
#pragma unroll
    for (int nt = 0; nt < 8; nt++) {
        int col = nt * 16 + n16;
#pragma unroll
        for (int r = 0; r < 4; r++) {
            int row = w * 16 + quad * 4 + r;
            fshT[col * 66 + row] = f2bs(f[nt][r]);
        }
    }
    __syncthreads();
    for (int idx = tid; idx < 64 * CNB; idx += 256) {
        int kl = idx / CNB, b = idx - kl * CNB;
        float acc3 = a.bbl[b];
        for (int d = 0; d < CIN; d++) acc3 += bs2f(fshT[d * 66 + kl]) * a.Wbl[d * CNB + b];
        a.out[OFF_B + (size_t)(e0 + kl) * CNB + b] = acc3;
    }
}

// ---------------- dispatch kernels -------------------------------------------------------------
__global__ __launch_bounds__(256) void k_prologue(KArgs a)
{
    __shared__ __align__(16) char smem[13440];
    int b = blockIdx.x, tid = threadIdx.x;
    if (b < 960) phase_pack(a, b * 256 + tid, 960 * 256);
    else if (b < 1088) phase_init_s(a, smem, b - 960, tid);
    else if (b < 1152) {
        int base = (b - 1088) * 1024;
#pragma unroll
        for (int q = 0; q < 4; q++) atomicAdd(&a.cnt[a.ii[base + q * 256 + tid]], 1);
    } else {  // jj degree count (only launched when use_vs)
        int base = (b - 1152) * 1024;
#pragma unroll
        for (int q = 0; q < 4; q++) atomicAdd(&a.cnt2[a.jj[base + q * 256 + tid]], 1);
    }
}
__global__ __launch_bounds__(256) void k_prefix(KArgs a, int vs)
{
    __shared__ int part[256];
    int b = blockIdx.x, tid = threadIdx.x;
    if (b == 1 && !vs) return;
    const int* src = b ? a.cnt2 : a.cnt;
    int* dst = b ? a.rowpos2 : a.rowpos;
    int loc[8], sum = 0;
#pragma unroll
    for (int q = 0; q < 8; q++) { loc[q] = src[tid * 8 + q]; sum += loc[q]; }
    part[tid] = sum;
    __syncthreads();
    if (tid == 0) { int r = 0; for (int i = 0; i < 256; i++) { int v = part[i]; part[i] = r; r += v; } }
    __syncthreads();
    int r = part[tid];
#pragma unroll
    for (int q = 0; q < 8; q++) {
        dst[tid * 8 + q] = r;
        if (!b) a.rowstart[tid * 8 + q] = r;
        r += loc[q];
    }
}
__global__ void k_perm(KArgs a, int vs)
{
    int k = blockIdx.x * 256 + threadIdx.x;
    int iv = a.ii[k];
    int p = atomicAdd(&a.rowpos[iv], 1);
    a.invp[k] = p;
    a.i_s[p] = iv;
    a.j_s[p] = a.jj[k];
    if (vs) {
        int jv = a.jj[k];
        int p2 = atomicAdd(&a.rowpos2[jv], 1);
        a.j_s2[p2] = jv;
        a.tgt2[p2] = p;
    }
}
// init_e (0..1023) + proj0 (1024..1151, signals nflag) + vscatter0 (1152..2175, polls nflag)
__global__ __launch_bounds__(256) void k_initE(KArgs a, int vs)
{
    __shared__ __align__(16) char smem[15360];
    int bid = blockIdx.x, tid = threadIdx.x;
    if (bid < 1024) phase_init_e(a, smem, bid, tid);
    else if (bid < 1152) {
        float s_reg[2][4];
        phase_node2(a, smem, bid - 1024, tid, false, false, false, false,
                    nullptr, nullptr, a.Wproj, s_reg, nullptr, 0, vs ? a.nflag : nullptr, 1);
    } else {
        phase_vscatter(a, smem, bid - 1152, tid, a.uvt0, a.pqt0, a.nflag, 1);
    }
}
// fused layer: em (0..1023, signals eflag) | node (1024..1151, polls eflag, signals nflag)
// | vscatter (1152..2175, polls nflag, writes NEXT layer's uvt/pqt buffer).
// em+node = 1152 < capacity 1280 and em depends on nothing -> deadlock-free under any order.
__global__ __launch_bounds__(256, 5) void k_layer(KArgs a, int gen, int ngen, int de, int dm,
        const short* We3p, const float* bedge_l, const short* W3mp, const float* bmsg_l,
        const short* Wpn_l, const float* bnode_l, const short* Wproj_slot, int dopost,
        const short* uvt_r, const short* pqt_r, short* uvt_w, short* pqt_w)
{
    __shared__ __align__(16) char smem[28160];
    int bid = blockIdx.x, tid = threadIdx.x;
    if (bid < 1024) {
        float e_reg[2][4];
        phase_em2(a, smem, bid, tid, de != 0, dm != 0, true, de != 0,
                  We3p, bedge_l, W3mp, bmsg_l, e_reg, a.eflag, gen, uvt_r, pqt_r);
    } else if (bid < 1152) {
        float s_reg[2][4];
        phase_node2(a, smem, bid - 1024, tid, true, dopost != 0, true, true,
                    Wpn_l, bnode_l, Wproj_slot, s_reg, a.eflag, gen,
                    ngen ? a.nflag : nullptr, ngen);
    } else {
        phase_vscatter(a, smem, bid - 1152, tid, uvt_w, pqt_w, a.nflag, ngen);
    }
}

// ---------------- fallback multi-kernel pieces -------------------------------------------------
__global__ __launch_bounds__(256) void k_init_e(KArgs a)
{
    __shared__ __align__(16) char smem[15360];
    phase_init_e(a, smem, blockIdx.x, threadIdx.x);
}
__global__ __launch_bounds__(256) void k_vscat(KArgs a, short* uvt, short* pqt)
{
    __shared__ __align__(16) char smem[512];
    phase_vscatter(a, smem, blockIdx.x, threadIdx.x, uvt, pqt, nullptr, 0);
}
__global__ __launch_bounds__(256) void k_node_proj(KArgs a, int donode, int dopost,
                                                   const short* Wpn_l, const float* bnode_l,
                                                   const short* Wproj_slot)
{
    __shared__ __align__(16) char smem[12800];
    float s_reg[2][4];
    phase_node2(a, smem, blockIdx.x, threadIdx.x, donode != 0, dopost != 0,
                donode != 0, donode != 0, Wpn_l, bnode_l, Wproj_slot, s_reg, nullptr, 0,
                nullptr, 0);
}
__global__ __launch_bounds__(256) void k_em(KArgs a, int de, int dm, const short* We3p,
                                            const float* bedge_l, const short* W3mp,
                                            const float* bmsg_l,
                                            const short* uvt_r, const short* pqt_r)
{
    __shared__ __align__(16) char smem[28160];
    float e_reg[2][4];
    phase_em2(a, smem, blockIdx.x, threadIdx.x, de != 0, dm != 0, true, de != 0,
              We3p, bedge_l, W3mp, bmsg_l, e_reg, nullptr, 0, uvt_r, pqt_r);
}
__global__ __launch_bounds__(256) void k_post_edge(KArgs a)
{
    __shared__ __align__(16) char smem[23040];
    phase_post_edge(a, smem, blockIdx.x, threadIdx.x);
}

extern "C" void kernel_launch(void* const* d_in, const int* in_sizes, int n_in,
                              void* d_out, int out_size, void* d_ws, size_t ws_size,
                              hipStream_t stream) {
    KArgs a;
    a.x      = (const float*)d_in[0];
    a.t      = (const float*)d_in[1];
    a.z      = (const float*)d_in[2];
    const int* eidx = (const int*)d_in[3];
    a.jj     = eidx;        // edge_index[0] = j
    a.ii     = eidx + NE;   // edge_index[1] = i
    a.ea     = (const float*)d_in[4];
    a.batch  = (const int*)d_in[5];
    a.beg    = (const int*)d_in[6];
    a.Wt_a   = (const float*)d_in[7];
    a.bt_a   = (const float*)d_in[8];
    a.Wt_b   = (const float*)d_in[9];
    a.bt_b   = (const float*)d_in[10];
    a.W_atom = (const float*)d_in[11];
    a.b_atom = (const float*)d_in[12];
    a.W_bond = (const float*)d_in[13];
    a.b_bond = (const float*)d_in[14];
    a.W_lat  = (const float*)d_in[15];
    a.b_lat  = (const float*)d_in[16];
    a.W_at   = (const float*)d_in[17];
    a.b_at   = (const float*)d_in[18];
    a.W_bt   = (const float*)d_in[19];
    a.b_bt   = (const float*)d_in[20];
    a.Wmsg   = (const float*)d_in[21];
    a.bmsg   = (const float*)d_in[22];
    a.Wnode  = (const float*)d_in[23];
    a.bnode  = (const float*)d_in[24];
    a.Wedge  = (const float*)d_in[25];
    a.bedge  = (const float*)d_in[26];
    a.Wsh    = (const float*)d_in[27];
    a.bsh    = (const float*)d_in[28];
    a.Wbm    = (const float*)d_in[29];
    a.bbm    = (const float*)d_in[30];
    a.Wbl    = (const float*)d_in[31];
    a.bbl    = (const float*)d_in[32];
    a.Wal    = (const float*)d_in[33];
    a.bal    = (const float*)d_in[34];

    a.s        = (float*)d_ws;
    a.e        = a.s + (size_t)NN * CIN;
    a.agg      = a.e + (size_t)NE * CED;             // [NN][4][CIN] f32 (4 MB)
    a.cnt      = (int*)(a.agg + (size_t)NN * 4 * CIN);
    a.pflag    = a.cnt + NN;
    a.eflag    = a.pflag + 256;
    a.cnt2     = a.eflag + 1024;
    a.nflag    = a.cnt2 + NN;                        // 128 tiles x 16-int (64B) spacing
    a.rowpos   = a.nflag + 2048;
    a.rowpos2  = a.rowpos + NN;
    a.rowstart = a.rowpos2 + NN;
    a.invp     = a.rowstart + NN;
    a.i_s      = a.invp + NE;
    a.j_s      = a.i_s + NE;
    a.j_s2     = a.j_s + NE;
    a.tgt2     = a.j_s2 + NE;
    a.s2       = (short*)(a.tgt2 + NE);              // bf16 arrays
    a.U        = a.s2 + (size_t)NN * CIN;
    a.V        = a.U + (size_t)NN * CIN;
    a.P        = a.V + (size_t)NN * CIN;
    a.Q        = a.P + (size_t)NN * CED;
    a.map      = (int*)(a.Q + (size_t)NN * CED);
    a.Wpn      = (short*)(a.map + (size_t)NN * NN);
    a.Wpsh     = a.Wpn + (size_t)NL * 8 * 8 * 64 * 8;
    a.Wpal     = a.Wpsh + (size_t)4 * 8 * 64 * 8;
    a.Wpbm     = a.Wpal + (size_t)4 * 5 * 64 * 8;
    a.Wproj    = a.Wpbm + (size_t)8 * 64 * 8;
    a.W3m      = a.Wproj + (size_t)6 * 4 * 20 * 64 * 8;
    a.We3      = a.W3m + (size_t)NL * 8 * 64 * 8;
    a.uvt0     = a.We3 + (size_t)NL * 2 * 64 * 8;    // 2 x NE x CIN bf16 (32 MB)
    a.pqt0     = a.uvt0 + (size_t)2 * NE * CIN;      // 2 x NE x CED bf16 (8 MB)
    a.out      = (float*)d_out;

    const size_t UVS = (size_t)NE * CIN;  // uvt buffer stride (shorts)
    const size_t PQS = (size_t)NE * CED;
    size_t need = (size_t)((char*)(a.pqt0 + 2 * PQS) - (char*)d_ws);
    int use_vs = (ws_size >= need) ? 1 : 0;

    static int mode = -1;
    if (mode < 0) {
        int dev = 0;
        (void)hipGetDevice(&dev);
        hipDeviceProp_t props;
        int ncu = 0;
        if (hipGetDeviceProperties(&props, dev) == hipSuccess) ncu = props.multiProcessorCount;
        int m1 = 0;
        if (hipOccupancyMaxActiveBlocksPerMultiprocessor(&m1, k_layer, 256, 0) != hipSuccess) m1 = 0;
        mode = ((long)m1 * ncu >= 1280) ? 1 : 0;
    }

    short* uvb[2] = { a.uvt0, a.uvt0 + UVS };
    short* pqb[2] = { a.pqt0, a.pqt0 + PQS };

    hipMemsetAsync(a.map, 0xFF, (size_t)NN * NN * sizeof(int), stream);
    hipMemsetAsync(a.agg, 0,
                   (size_t)NN * 4 * CIN * sizeof(float) +
                   (NN + 256 + 1024 + NN + 2048) * sizeof(int),
                   stream);   // agg + cnt + pflag + eflag + cnt2 + nflag

    k_prologue<<<use_vs ? 1216 : 1152, 256, 0, stream>>>(a);
    k_prefix<<<2, 256, 0, stream>>>(a, use_vs);
    k_perm<<<NE / 256, 256, 0, stream>>>(a, use_vs);

    if (mode) {
        k_initE<<<use_vs ? 2176 : 1152, 256, 0, stream>>>(a, use_vs);
        for (int k = 0; k < NL; k++) {
            int de = (k > 0) ? 1 : 0;
            const short* ur = use_vs ? uvb[k & 1] : nullptr;
            const short* pr = use_vs ? pqb[k & 1] : nullptr;
            k_layer<<<use_vs ? 2176 : 1152, 256, 0, stream>>>(a, k + 1, use_vs ? (k + 2) : 0,
                de, 1,
                de ? a.We3 + (size_t)(k - 1) * 2 * 64 * 8 : a.We3,
                de ? a.bedge + (k - 1) * CED : a.bedge,
                a.W3m + (size_t)k * 8 * 64 * 8, a.bmsg + k * CIN,
                a.Wpn + (size_t)k * 8 * 8 * 64 * 8, a.bnode + k * CIN,
                a.Wproj + (size_t)(k + 1) * 4 * 20 * 64 * 8, (k == NL - 1) ? 1 : 0,
                ur, pr, uvb[(k + 1) & 1], pqb[(k + 1) & 1]);
        }
        // final edge-only update (reads P/Q of node(NL-1); pqt parity 1)
        k_layer<<<1024, 256, 0, stream>>>(a, NL + 1, 0, 1, 0,
            a.We3 + (size_t)(NL - 1) * 2 * 64 * 8, a.bedge + (NL - 1) * CED,
            a.W3m, a.bmsg, a.Wpn, a.bnode, a.Wproj, 0,
            use_vs ? uvb[1] : nullptr, use_vs ? pqb[1] : nullptr, nullptr, nullptr);
    } else {
        k_init_e<<<1024, 256, 0, stream>>>(a);
        k_node_proj<<<NN / 16, 256, 0, stream>>>(a, 0, 0, nullptr, nullptr, a.Wproj);
        if (use_vs) k_vscat<<<1024, 256, 0, stream>>>(a, uvb[0], pqb[0]);
        for (int k = 0; k < NL; k++) {
            int de = (k > 0) ? 1 : 0;
            k_em<<<1024, 256, 0, stream>>>(a, de, 1,
                de ? a.We3 + (size_t)(k - 1) * 2 * 64 * 8 : a.We3,
                de ? a.bedge + (k - 1) * CED : a.bedge,
                a.W3m + (size_t)k * 8 * 64 * 8, a.bmsg + k * CIN,
                use_vs ? uvb[k & 1] : nullptr, use_vs ? pqb[k & 1] : nullptr);
            k_node_proj<<<NN / 16, 256, 0, stream>>>(a, 1, (k == NL - 1) ? 1 : 0,
                a.Wpn + (size_t)k * 8 * 8 * 64 * 8, a.bnode + k * CIN,
                a.Wproj + (size_t)(k + 1) * 4 * 20 * 64 * 8);
            if (use_vs) k_vscat<<<1024, 256, 0, stream>>>(a, uvb[(k + 1) & 1], pqb[(k + 1) & 1]);
        }
        k_em<<<1024, 256, 0, stream>>>(a, 1, 0,
            a.We3 + (size_t)(NL - 1) * 2 * 64 * 8, a.bedge + (NL - 1) * CED,
            a.W3m, a.bmsg,
            use_vs ? uvb[1] : nullptr, use_vs ? pqb[1] : nullptr);
    }
    k_post_edge<<<NE / 64, 256, 0, stream>>>(a);
}

// Round 11
// 336.523 us; speedup vs baseline: 1.1742x; 1.1742x over previous
//
#include <hip/hip_runtime.h>
#include <hip/hip_bf16.h>

#define NN 2048
#define NE 65536
#define NG 32
#define CIN 128
#define CED 32
#define CLAT 64
#define CFA 16
#define CNB 5
#define NL 5

#define OFF_AT (NN * CLAT)
#define OFF_B  (NN * CLAT + NN * CFA)

typedef __attribute__((ext_vector_type(8))) short bf16x8;
typedef __attribute__((ext_vector_type(4))) float f32x4;

__device__ __forceinline__ float silu_f(float v) { return v / (1.0f + __expf(-v)); }
__device__ __forceinline__ short f2bs(float v) {
    __hip_bfloat16 h = __float2bfloat16(v);
    return *reinterpret_cast<short*>(&h);
}
__device__ __forceinline__ float bs2f(short s) {
    return __bfloat162float(*reinterpret_cast<__hip_bfloat16*>(&s));
}
__device__ __forceinline__ unsigned pack2(float a, float b) {
    return ((unsigned)(unsigned short)f2bs(b) << 16) | (unsigned short)f2bs(a);
}
__device__ __forceinline__ unsigned addpack(unsigned ua, unsigned va) {
    float a0 = bs2f((short)(ua & 0xffff)), a1 = bs2f((short)(ua >> 16));
    float b0 = bs2f((short)(va & 0xffff)), b1 = bs2f((short)(va >> 16));
    return pack2(a0 + b0, a1 + b1);
}

struct KArgs {
    const float *x, *t, *z;
    const int *jj, *ii;           // edge_index rows 0 (j) and 1 (i)
    const float *ea;
    const int *batch, *beg;
    const float *Wt_a, *bt_a, *Wt_b, *bt_b, *W_atom, *b_atom, *W_bond, *b_bond;
    const float *W_lat, *b_lat, *W_at, *b_at, *W_bt, *b_bt;
    const float *Wmsg, *bmsg, *Wnode, *bnode, *Wedge, *bedge;
    const float *Wsh, *bsh, *Wbm, *bbm, *Wbl, *bbl, *Wal, *bal;
    float *s, *e;
    float *agg;                   // partial sums: [NN][4][CIN] f32, slot-indexed, no atomics
    int *cnt, *pflag, *eflag, *rowpos, *rowstart, *invp, *i_s, *j_s;
    short *s2, *U, *V, *P, *Q;    // bf16 storage
    int *map;
    short *Wpn, *Wpsh, *Wpal, *Wpbm, *Wproj, *W3m, *We3;
    float *out;
};

// ---------------- phase: pack weights (strided) ------------------------------------------------
__device__ __forceinline__ void phase_pack(const KArgs& a, int start, int stride)
{
    for (int idx = start; idx < 6 * 4 * 20 * 64 * 8; idx += stride) {
        int j = idx & 7, t0 = idx >> 3, lane = t0 & 63, tt = t0 >> 6;
        int kq = (lane >> 4) * 8 + j, n16 = lane & 15;
        if (idx < NL * 8 * 8 * 64 * 8) { // Wnode K=256 N=128
            int nt = tt & 7, kt = (tt >> 3) & 7, l = tt >> 6;
            a.Wpn[idx] = f2bs(a.Wnode[((size_t)l * 256 + kt * 32 + kq) * CIN + nt * 16 + n16]);
        }
        if (idx < 4 * 8 * 64 * 8) { // Wsh K=128 N=128
            int nt = tt & 7, kt = tt >> 3;
            a.Wpsh[idx] = f2bs(a.Wsh[(size_t)(kt * 32 + kq) * CIN + nt * 16 + n16]);
        }
        if (idx < 4 * 5 * 64 * 8) { // Wal K=128 N=80
            int nt = tt % 5, kt = tt / 5;
            a.Wpal[idx] = f2bs(a.Wal[(size_t)(kt * 32 + kq) * 80 + nt * 16 + n16]);
        }
        if (idx < 8 * 64 * 8) { // Wbm K=32 N=128
            int nt = tt & 7;
            a.Wpbm[idx] = f2bs(a.Wbm[(size_t)kq * CIN + nt * 16 + n16]);
        }
        { // Wproj: 6 slots, K=128, N=320 (bound == loop bound)
            int nt = tt % 20; int t2 = tt / 20; int kt = t2 & 3; int slot = t2 >> 2;
            int k = kt * 32 + kq;
            float v;
            if (nt < 16) {
                int msgl = slot % 5;
                int srcK = (nt < 8) ? k : 128 + k;
                int col = (nt & 7) * 16 + n16;
                v = a.Wmsg[((size_t)msgl * 288 + srcK) * CIN + col];
            } else {
                int edgel = (slot == 0) ? 0 : slot - 1;
                int srcK = (nt < 18) ? k : 128 + k;
                int col = (nt & 1) * 16 + n16;
                v = a.Wedge[((size_t)edgel * 288 + srcK) * CED + col];
            }
            a.Wproj[idx] = f2bs(v);
        }
        if (idx < NL * 8 * 64 * 8) { // W3m: Wmsg rows 256..287, K=32 N=128
            int nt = tt & 7, l = tt >> 3;
            a.W3m[idx] = f2bs(a.Wmsg[((size_t)l * 288 + 256 + kq) * CIN + nt * 16 + n16]);
        }
        if (idx < NL * 2 * 64 * 8) { // We3: Wedge rows 256..287, K=32 N=32
            int nt = tt & 1, l = tt >> 1;
            a.We3[idx] = f2bs(a.Wedge[((size_t)l * 288 + 256 + kq) * CED + nt * 16 + n16]);
        }
    }
}

// ---------------- phase: init s (16 nodes per tile) --------------------------------------------
__device__ __forceinline__ void phase_init_s(const KArgs& a, char* smem, int tile, int tid)
{
    float* xs  = (float*)smem;            // 16*16
    float* zs  = (float*)(smem + 1024);   // 16*64
    float* tmp = (float*)(smem + 5120);   // 16*128
    float* tv  = (float*)(smem + 13312);  // 16
    int nb0 = tile * 16;
    int c = tid & 127, h = tid >> 7;
    if (tid < 16 * CFA / 4) ((float4*)xs)[tid] = ((const float4*)a.x)[nb0 * (CFA / 4) + tid];
    if (tid < 16 * CLAT / 4) ((float4*)zs)[tid] = ((const float4*)a.z)[nb0 * (CLAT / 4) + tid];
    if (tid < 16) tv[tid] = a.t[a.batch[nb0 + tid]];
    __syncthreads();
    float wta = a.Wt_a[c], base0 = a.b_atom[c] + a.bt_a[c];
    float acc[8];
#pragma unroll
    for (int q = 0; q < 8; q++) acc[q] = base0 + tv[h * 8 + q] * wta;
    for (int k = 0; k < CFA; k++) {
        float w = a.W_atom[k * CIN + c];
#pragma unroll
        for (int q = 0; q < 8; q++) acc[q] += xs[(h * 8 + q) * CFA + k] * w;
    }
#pragma unroll
    for (int q = 0; q < 8; q++) tmp[(h * 8 + q) * CIN + c] = acc[q];
    __syncthreads();
    float base1 = a.b_at[c] + a.b_lat[c];
    float acc2[8];
#pragma unroll
    for (int q = 0; q < 8; q++) acc2[q] = base1;
    for (int k4 = 0; k4 < CIN / 4; k4++) {
        float w0 = a.W_at[(4 * k4 + 0) * CIN + c], w1 = a.W_at[(4 * k4 + 1) * CIN + c];
        float w2 = a.W_at[(4 * k4 + 2) * CIN + c], w3 = a.W_at[(4 * k4 + 3) * CIN + c];
#pragma unroll
        for (int q = 0; q < 8; q++) {
            float4 f = *(const float4*)&tmp[(h * 8 + q) * CIN + 4 * k4];
            acc2[q] += f.x * w0 + f.y * w1 + f.z * w2 + f.w * w3;
        }
    }
    for (int k4 = 0; k4 < CLAT / 4; k4++) {
        float w0 = a.W_lat[(4 * k4 + 0) * CIN + c], w1 = a.W_lat[(4 * k4 + 1) * CIN + c];
        float w2 = a.W_lat[(4 * k4 + 2) * CIN + c], w3 = a.W_lat[(4 * k4 + 3) * CIN + c];
#pragma unroll
        for (int q = 0; q < 8; q++) {
            float4 f = *(const float4*)&zs[(h * 8 + q) * CLAT + 4 * k4];
            acc2[q] += f.x * w0 + f.y * w1 + f.z * w2 + f.w * w3;
        }
    }
#pragma unroll
    for (int q = 0; q < 8; q++) {
        int nd = nb0 + h * 8 + q;
        a.s[(size_t)nd * CIN + c] = acc2[q];
    }
}

// ---------------- phase: init e tile (64 edges), sorted-order write ----------------------------
__device__ __forceinline__ void phase_init_e(const KArgs& a, char* smem, int tb, int tid)
{
    float* eas   = (float*)smem;            // 320
    float* tv    = (float*)(smem + 1280);   // 64
    int*   sp    = (int*)(smem + 1536);     // 64
    float* tmp   = (float*)(smem + 1792);   // 64*33
    float* wbt   = (float*)(smem + 10240);  // 1024
    float* wbond = (float*)(smem + 14336);  // 160
    float* cb    = (float*)(smem + 14976);
    float* wtb   = (float*)(smem + 15104);
    float* bbt2  = (float*)(smem + 15232);
    int k0 = tb * 64;
    for (int idx = tid; idx < 320; idx += 256) eas[idx] = a.ea[(size_t)k0 * 5 + idx];
    if (tid < 64) { tv[tid] = a.t[a.beg[k0 + tid]]; sp[tid] = a.invp[k0 + tid]; }
    for (int idx = tid; idx < 1024; idx += 256) wbt[idx] = a.W_bt[idx];
    if (tid < 160) wbond[tid] = a.W_bond[tid];
    if (tid < 32) { cb[tid] = a.b_bond[tid] + a.bt_b[tid]; wtb[tid] = a.Wt_b[tid]; bbt2[tid] = a.b_bt[tid]; }
    __syncthreads();
    int ch = tid & 31, eg = tid >> 5;
#pragma unroll
    for (int q = 0; q < 8; q++) {
        int le = eg * 8 + q;
        float acc = cb[ch] + tv[le] * wtb[ch];
#pragma unroll
        for (int bb = 0; bb < CNB; bb++) acc += eas[le * 5 + bb] * wbond[bb * 32 + ch];
        tmp[le * 33 + ch] = acc;
    }
    __syncthreads();
#pragma unroll
    for (int q = 0; q < 8; q++) {
        int le = eg * 8 + q;
        float acc2 = bbt2[ch];
        for (int d = 0; d < 32; d++) acc2 += tmp[le * 33 + d] * wbt[d * 32 + ch];
        size_t ix = (size_t)sp[le] * CED + ch;
        a.e[ix] = acc2;
        if (ch == 0) {
            int k = k0 + le;
            atomicMax(&a.map[(size_t)a.jj[k] * NN + a.ii[k]], k); // numpy last-write-wins
        }
    }
}

// ---------------- phase: node update + projections (16 nodes/tile) -----------------------------
// When eflag != null: spins on per-em-tile flags covering this tile's sorted edge range (same
// dispatch producer-consumer), then acquire-fences before reading agg.
__device__ __forceinline__ void phase_node2(
    const KArgs& a, char* smem, int tile, int tid, bool DO_NODE, bool DO_POST,
    bool LOAD_S, bool STORE_S,
    const short* Wpn_l, const float* bnode_l, const short* Wproj_slot, float (*s_reg)[4],
    const int* eflag, int gen)
{
    short* feat  = (short*)smem;            // 16*264 (aliased as feat_s2 in post phase)
    short* feat2 = (short*)(smem + 8448);   // 16*136
    int nb0 = tile * 16;
    int lane = tid & 63, w = tid >> 6;
    int quad = lane >> 4, n16 = lane & 15;

    if (DO_NODE) {
        if (eflag) {
            if (tid == 0) {
                int r0 = a.rowstart[nb0];
                int ed = (nb0 + 16 < NN) ? a.rowstart[nb0 + 16] : NE;
                if (ed > r0) {
                    int t1 = (ed - 1) >> 6;
                    for (int t = r0 >> 6; t <= t1; t++)
                        while (__hip_atomic_load(&eflag[t], __ATOMIC_RELAXED, __HIP_MEMORY_SCOPE_AGENT) < gen)
                            __builtin_amdgcn_s_sleep(2);
                }
            }
            __syncthreads();
            __threadfence();   // acquire: invalidate stale L1/L2 before reading remote agg
        }
#pragma unroll
        for (int n2 = 0; n2 < 2; n2++) {
            int col = (w * 2 + n2) * 16 + n16;
#pragma unroll
            for (int r = 0; r < 4; r++) {
                int row = quad * 4 + r;
                if (LOAD_S) s_reg[n2][r] = a.s[(size_t)(nb0 + row) * CIN + col];
                feat[row * 264 + col] = f2bs(s_reg[n2][r]);
            }
        }
        // consume partial sums agg[node][slot 0..3][c]; no re-zero needed: the same em tiles
        // rewrite the same slots every layer; untouched slots stay 0 from the per-iter memset.
#pragma unroll
        for (int k2 = 0; k2 < 2; k2++) {
            int idx = tid + k2 * 256;            // 16*32 float4 lanes
            int kl = idx >> 5, c = idx & 31;
            size_t base = (size_t)(nb0 + kl) * 128 + c;   // float4 units; slot stride 32
            float4 p0 = ((const float4*)a.agg)[base];
            float4 p1 = ((const float4*)a.agg)[base + 32];
            float4 p2 = ((const float4*)a.agg)[base + 64];
            float4 p3 = ((const float4*)a.agg)[base + 96];
            float4 v; v.x = p0.x + p1.x + p2.x + p3.x; v.y = p0.y + p1.y + p2.y + p3.y;
            v.z = p0.z + p1.z + p2.z + p3.z; v.w = p0.w + p1.w + p2.w + p3.w;
            uint2 p; p.x = pack2(v.x, v.y); p.y = pack2(v.z, v.w);
            *(uint2*)&feat[kl * 264 + 128 + 4 * c] = p;
        }
        __syncthreads();
        f32x4 acc[2];
        acc[0] = (f32x4){0.f, 0.f, 0.f, 0.f};
        acc[1] = (f32x4){0.f, 0.f, 0.f, 0.f};
        const short* fbase = feat + n16 * 264 + quad * 8;
#pragma unroll
        for (int kt = 0; kt < 8; kt++) {
            bf16x8 av = *(const bf16x8*)(fbase + kt * 32);
#pragma unroll
            for (int n2 = 0; n2 < 2; n2++) {
                int nt = w * 2 + n2;
                bf16x8 b = *(const bf16x8*)(Wpn_l + ((size_t)(kt * 8 + nt) * 64 + lane) * 8);
                acc[n2] = __builtin_amdgcn_mfma_f32_16x16x32_bf16(av, b, acc[n2], 0, 0, 0);
            }
        }
#pragma unroll
        for (int n2 = 0; n2 < 2; n2++) {
            int col = (w * 2 + n2) * 16 + n16;
            float bb = bnode_l[col];
#pragma unroll
            for (int r = 0; r < 4; r++) {
                int row = quad * 4 + r;
                float v = s_reg[n2][r] + silu_f(acc[n2][r] + bb);
                s_reg[n2][r] = v;
                if (STORE_S) a.s[(size_t)(nb0 + row) * CIN + col] = v;
                feat2[row * 136 + col] = f2bs(v);
            }
        }
        __syncthreads();
    } else {
        int kl = tid >> 4, c = tid & 15;
        const float4* sp4 = (const float4*)&a.s[(size_t)(nb0 + kl) * CIN + c * 8];
        float4 v0 = sp4[0], v1 = sp4[1];
        uint4 p; p.x = pack2(v0.x, v0.y); p.y = pack2(v0.z, v0.w);
        p.z = pack2(v1.x, v1.y); p.w = pack2(v1.z, v1.w);
        *(uint4*)&feat2[kl * 136 + c * 8] = p;
        __syncthreads();
    }

    // projections: [U|V|P|Q] = s_new @ Wproj (K=128, N=320); wave w -> nt 5w..5w+4
    {
        f32x4 accp[5];
#pragma unroll
        for (int t2 = 0; t2 < 5; t2++) accp[t2] = (f32x4){0.f, 0.f, 0.f, 0.f};
        const short* abase = feat2 + n16 * 136 + quad * 8;
#pragma unroll
        for (int kt = 0; kt < 4; kt++) {
            bf16x8 av = *(const bf16x8*)(abase + kt * 32);
#pragma unroll
            for (int n5 = 0; n5 < 5; n5++) {
                int nt = w * 5 + n5;
                bf16x8 b = *(const bf16x8*)(Wproj_slot + ((size_t)(kt * 20 + nt) * 64 + lane) * 8);
                accp[n5] = __builtin_amdgcn_mfma_f32_16x16x32_bf16(av, b, accp[n5], 0, 0, 0);
            }
        }
#pragma unroll
        for (int n5 = 0; n5 < 5; n5++) {
            int nt = w * 5 + n5;
#pragma unroll
            for (int r = 0; r < 4; r++) {
                int node = tile * 16 + quad * 4 + r;
                short bv = f2bs(accp[n5][r]);
                if (nt < 8)       a.U[(size_t)node * CIN + nt * 16 + n16] = bv;
                else if (nt < 16) a.V[(size_t)node * CIN + (nt - 8) * 16 + n16] = bv;
                else if (nt < 18) a.P[(size_t)node * CED + (nt - 16) * 16 + n16] = bv;
                else              a.Q[(size_t)node * CED + (nt - 18) * 16 + n16] = bv;
            }
        }
    }

    if (DO_POST) {
        short* feat_s2 = feat;
        const short* fbase = feat2 + n16 * 136 + quad * 8;
        f32x4 acc[2];
        acc[0] = (f32x4){0.f, 0.f, 0.f, 0.f};
        acc[1] = (f32x4){0.f, 0.f, 0.f, 0.f};
#pragma unroll
        for (int kt = 0; kt < 4; kt++) {
            bf16x8 av = *(const bf16x8*)(fbase + kt * 32);
#pragma unroll
            for (int n2 = 0; n2 < 2; n2++) {
                int nt = w * 2 + n2;
                bf16x8 b = *(const bf16x8*)(a.Wpsh + ((size_t)(kt * 8 + nt) * 64 + lane) * 8);
                acc[n2] = __builtin_amdgcn_mfma_f32_16x16x32_bf16(av, b, acc[n2], 0, 0, 0);
            }
        }
#pragma unroll
        for (int n2 = 0; n2 < 2; n2++) {
            int col = (w * 2 + n2) * 16 + n16;
            float bb = a.bsh[col];
#pragma unroll
            for (int r = 0; r < 4; r++) {
                int row = quad * 4 + r;
                float v = silu_f(acc[n2][r] + bb);
                short bv = f2bs(v);
                a.s2[(size_t)(nb0 + row) * CIN + col] = bv;
                feat_s2[row * 136 + col] = bv;
            }
        }
        __syncthreads();
        const short* abase2 = feat_s2 + n16 * 136 + quad * 8;
        f32x4 acca[2];
        acca[0] = (f32x4){0.f, 0.f, 0.f, 0.f};
        acca[1] = (f32x4){0.f, 0.f, 0.f, 0.f};
        int nAl = (w == 0) ? 2 : 1;
        int ntl[2] = {w, 4};
#pragma unroll
        for (int kt = 0; kt < 4; kt++) {
            bf16x8 av = *(const bf16x8*)(abase2 + kt * 32);
#pragma unroll
            for (int q = 0; q < 2; q++) {
                if (q < nAl) {
                    bf16x8 b = *(const bf16x8*)(a.Wpal + ((size_t)(kt * 5 + ntl[q]) * 64 + lane) * 8);
                    acca[q] = __builtin_amdgcn_mfma_f32_16x16x32_bf16(av, b, acca[q], 0, 0, 0);
                }
            }
        }
#pragma unroll
        for (int q = 0; q < 2; q++) {
            if (q < nAl) {
                int col = ntl[q] * 16 + n16;
                float bb = a.bal[col];
#pragma unroll
                for (int r = 0; r < 4; r++) {
                    int node = nb0 + quad * 4 + r;
                    float v = acca[q][r] + bb;
                    if (col < CFA) a.out[OFF_AT + node * CFA + col] = v;
                    else           a.out[(size_t)node * CLAT + (col - CFA)] = v;
                }
            }
        }
    }
}

// ---------------- phase: per-edge tile (64 sorted edges) ---------------------------------------
// When eflag != null and DO_MSG: release-signals eflag[tb] = gen after partial-sum writes.
// LDS: feat_e 5120 | uv_bf 17408 | pq_bf 5120 | sii 256 | sjj 256 = 28160 B
__device__ __forceinline__ void phase_em2(
    const KArgs& a, char* smem, int tb, int tid, bool DO_EDGE, bool DO_MSG, bool LOAD_E, bool WRITE_E,
    const short* We3p, const float* bedge_l, const short* W3mp, const float* bmsg_l,
    float (*e_reg)[4], int* eflag, int gen)
{
    short* feat_e = (short*)smem;             // 64*40 bf16
    short* uv_bf  = (short*)(smem + 5120);    // 64*136 bf16 (U[i]+V[j]; then m values)
    short* pq_bf  = (short*)(smem + 22528);   // 64*40 bf16 (P[i]+Q[j])
    int*   sii    = (int*)(smem + 27648);     // 64
    int*   sjj    = (int*)(smem + 27904);     // 64
    int e0 = tb * 64;
    int lane = tid & 63, w = tid >> 6;
    int quad = lane >> 4, n16 = lane & 15;
    if (tid < 64) sii[tid] = a.i_s[e0 + tid];
    else if (tid < 128) sjj[tid - 64] = a.j_s[e0 + tid - 64];
    __syncthreads();
#pragma unroll
    for (int nt = 0; nt < 2; nt++) {
        int ch = nt * 16 + n16;
#pragma unroll
        for (int r = 0; r < 4; r++) {
            int el = w * 16 + quad * 4 + r;
            if (LOAD_E) e_reg[nt][r] = a.e[(size_t)(e0 + el) * CED + ch];
            feat_e[el * 40 + ch] = f2bs(e_reg[nt][r]);
        }
    }
    if (DO_EDGE) {
        uint2 pa[2], qb[2];
#pragma unroll
        for (int k2 = 0; k2 < 2; k2++) {
            int idx = tid + k2 * 256;
            int kl = idx >> 3, c = idx & 7;
            pa[k2] = ((const uint2*)a.P)[(size_t)sii[kl] * 8 + c];
            qb[k2] = ((const uint2*)a.Q)[(size_t)sjj[kl] * 8 + c];
        }
#pragma unroll
        for (int k2 = 0; k2 < 2; k2++) {
            int idx = tid + k2 * 256;
            int kl = idx >> 3, c = idx & 7;
            uint2 o; o.x = addpack(pa[k2].x, qb[k2].x); o.y = addpack(pa[k2].y, qb[k2].y);
            *(uint2*)&pq_bf[kl * 40 + 4 * c] = o;
        }
    }
    if (DO_MSG) {
        uint4 ua[4], va[4];
#pragma unroll
        for (int k2 = 0; k2 < 4; k2++) {
            int idx = tid + k2 * 256;
            int kl = idx >> 4, c = idx & 15;
            ua[k2] = ((const uint4*)a.U)[(size_t)sii[kl] * 16 + c];
            va[k2] = ((const uint4*)a.V)[(size_t)sjj[kl] * 16 + c];
        }
#pragma unroll
        for (int k2 = 0; k2 < 4; k2++) {
            int idx = tid + k2 * 256;
            int kl = idx >> 4, c = idx & 15;
            uint4 o; o.x = addpack(ua[k2].x, va[k2].x); o.y = addpack(ua[k2].y, va[k2].y);
            o.z = addpack(ua[k2].z, va[k2].z); o.w = addpack(ua[k2].w, va[k2].w);
            *(uint4*)&uv_bf[kl * 136 + c * 8] = o;
        }
    }
    __syncthreads();
    const short* abase = feat_e + (w * 16 + n16) * 40 + quad * 8;
    bf16x8 av = *(const bf16x8*)abase;

    if (DO_EDGE) {
        f32x4 acc_e[2];
        acc_e[0] = (f32x4){0.f, 0.f, 0.f, 0.f};
        acc_e[1] = (f32x4){0.f, 0.f, 0.f, 0.f};
#pragma unroll
        for (int nt = 0; nt < 2; nt++) {
            bf16x8 b = *(const bf16x8*)(We3p + ((size_t)(nt * 64 + lane)) * 8);
            acc_e[nt] = __builtin_amdgcn_mfma_f32_16x16x32_bf16(av, b, acc_e[nt], 0, 0, 0);
        }
#pragma unroll
        for (int nt = 0; nt < 2; nt++) {
            int ch = nt * 16 + n16;
            float bb = bedge_l[ch];
#pragma unroll
            for (int r = 0; r < 4; r++) {
                int el = w * 16 + quad * 4 + r;
                float v = e_reg[nt][r] + silu_f(acc_e[nt][r] + bb + bs2f(pq_bf[el * 40 + ch]));
                e_reg[nt][r] = v;
                feat_e[el * 40 + ch] = f2bs(v);
                if (WRITE_E) a.e[(size_t)(e0 + el) * CED + ch] = v;
            }
        }
        av = *(const bf16x8*)abase; // re-read own-wave patched row
    }

    if (DO_MSG) {
        f32x4 acc_m[8];
#pragma unroll
        for (int t2 = 0; t2 < 8; t2++) acc_m[t2] = (f32x4){0.f, 0.f, 0.f, 0.f};
#pragma unroll
        for (int nt = 0; nt < 8; nt++) {
            bf16x8 b = *(const bf16x8*)(W3mp + ((size_t)(nt * 64 + lane)) * 8);
            acc_m[nt] = __builtin_amdgcn_mfma_f32_16x16x32_bf16(av, b, acc_m[nt], 0, 0, 0);
        }
#pragma unroll
        for (int nt = 0; nt < 8; nt++) {
            int ch = nt * 16 + n16;
            float bb = bmsg_l[ch];
#pragma unroll
            for (int r = 0; r < 4; r++) {
                int el = w * 16 + quad * 4 + r;
                int lix = el * 136 + ch;
                float m = silu_f(acc_m[nt][r] + bb + bs2f(uv_bf[lix]));
                uv_bf[lix] = f2bs(m);
            }
        }
        __syncthreads();
        // group-reduce by sorted target -> per-tile partial rows (race-free slot per tile)
        if (tid < 128) {
            int c = tid;
            float run = 0.f;
            int cur = sii[0];
            for (int r = 0; r < 64; r++) {
                int tg = sii[r];
                if (tg != cur) {
                    int slot = tb - (a.rowstart[cur] >> 6); slot = (slot > 3) ? 3 : slot;
                    a.agg[((size_t)cur * 4 + slot) * CIN + c] = run;
                    run = 0.f; cur = tg;
                }
                run += bs2f(uv_bf[r * 136 + c]);
            }
            int slot = tb - (a.rowstart[cur] >> 6); slot = (slot > 3) ? 3 : slot;
            a.agg[((size_t)cur * 4 + slot) * CIN + c] = run;
        }
        if (eflag) {
            __syncthreads();
            if (tid == 0) {
                __threadfence();   // release before flag store
                __hip_atomic_store(&eflag[tb], gen, __ATOMIC_RELAXED, __HIP_MEMORY_SCOPE_AGENT);
            }
        }
    }
}

// ---------------- phase: post edge tile (64 edges, original order); bf16 staging ---------------
// LDS: esym 5120 | sbias/fshT 16896 | 4x256 idx = 23040 B
__device__ __forceinline__ void phase_post_edge(const KArgs& a, char* smem, int tb, int tid)
{
    short* esym  = (short*)smem;             // 64*40
    short* sbias = (short*)(smem + 5120);    // [64][132] bf16; aliased as fshT [128][66] bf16
    int* sii = (int*)(smem + 22016);
    int* sjj = (int*)(smem + 22272);
    int* skf = (int*)(smem + 22528);
    int* skb = (int*)(smem + 22784);
    int e0 = tb * 64;
    if (tid < 64) sii[tid] = a.ii[e0 + tid];
    else if (tid < 128) sjj[tid - 64] = a.jj[e0 + tid - 64];
    __syncthreads();
    if (tid < 64) skf[tid] = a.invp[a.map[(size_t)sjj[tid] * NN + sii[tid]]];
    else if (tid < 128) {
        int m = a.map[(size_t)sii[tid - 64] * NN + sjj[tid - 64]];
        skb[tid - 64] = (m >= 0) ? a.invp[m] : -1;
    }
    __syncthreads();
    {
        float4 av2[2], bv2[2];
#pragma unroll
        for (int k2 = 0; k2 < 2; k2++) {
            int idx = tid + k2 * 256;
            int kl = idx >> 3, c = idx & 7;
            av2[k2] = ((const float4*)a.e)[(size_t)skf[kl] * 8 + c];
            int kb = skb[kl];
            bv2[k2] = (float4){0.f, 0.f, 0.f, 0.f};
            if (kb >= 0) bv2[k2] = ((const float4*)a.e)[(size_t)kb * 8 + c];
        }
#pragma unroll
        for (int k2 = 0; k2 < 2; k2++) {
            int idx = tid + k2 * 256;
            int kl = idx >> 3, c = idx & 7;
            uint2 p; p.x = pack2(0.5f * (av2[k2].x + bv2[k2].x), 0.5f * (av2[k2].y + bv2[k2].y));
            p.y = pack2(0.5f * (av2[k2].z + bv2[k2].z), 0.5f * (av2[k2].w + bv2[k2].w));
            *(uint2*)&esym[kl * 40 + 4 * c] = p;
        }
    }
#pragma unroll
    for (int half = 0; half < 2; half++) {
        uint2 av4[4], bv4[4];
#pragma unroll
        for (int k2 = 0; k2 < 4; k2++) {
            int idx = tid + (half * 4 + k2) * 256;
            int kl = idx >> 5, c = idx & 31;
            av4[k2] = ((const uint2*)a.s2)[(size_t)sii[kl] * 32 + c];
            bv4[k2] = ((const uint2*)a.s2)[(size_t)sjj[kl] * 32 + c];
        }
#pragma unroll
        for (int k2 = 0; k2 < 4; k2++) {
            int idx = tid + (half * 4 + k2) * 256;
            int kl = idx >> 5, c = idx & 31;
            uint2 o; o.x = addpack(av4[k2].x, bv4[k2].x); o.y = addpack(av4[k2].y, bv4[k2].y);
            *(uint2*)&sbias[kl * 132 + 4 * c] = o;
        }
    }
    __syncthreads();
    int lane = tid & 63, w = tid >> 6;
    int quad = lane >> 4, n16 = lane & 15;
    bf16x8 av = *(const bf16x8*)(esym + (w * 16 + n16) * 40 + quad * 8);
    f32x4 acc[8];
#pragma unroll
    for (int nt = 0; nt < 8; nt++) {
        bf16x8 b = *(const bf16x8*)(a.Wpbm + ((size_t)nt * 64 + lane) * 8);
        f32x4 zero = {0.f, 0.f, 0.f, 0.f};
        acc[nt] = __builtin_amdgcn_mfma_f32_16x16x32_bf16(av, b, zero, 0, 0, 0);
    }
    float f[8][4];
#pragma unroll
    for (int nt = 0; nt < 8; nt++) {
        int col = nt * 16 + n16;
        float bb = a.bbm[col];
#pragma unroll
        for (int r = 0; r < 4; r++) {
            int row = w * 16 + quad * 4 + r;
            f[nt][r] = silu_f(acc[nt][r] + bb + bs2f(sbias[row * 132 + col]));
        }
    }
    __syncthreads();
    short* fshT = sbias; // [128][66] bf16
#pragma unroll
    for (int nt = 0; nt < 8; nt++) {
        int col = nt * 16 + n16;
#pragma unroll
        for (int r = 0; r < 4; r++) {
            int row = w * 16 + quad * 4 + r;
            fshT[col * 66 + row] = f2bs(f[nt][r]);
        }
    }
    __syncthreads();
    for (int idx = tid; idx < 64 * CNB; idx += 256) {
        int kl = idx / CNB, b = idx - kl * CNB;
        float acc3 = a.bbl[b];
        for (int d = 0; d < CIN; d++) acc3 += bs2f(fshT[d * 66 + kl]) * a.Wbl[d * CNB + b];
        a.out[OFF_B + (size_t)(e0 + kl) * CNB + b] = acc3;
    }
}

// ---------------- dispatch kernels -------------------------------------------------------------
__global__ __launch_bounds__(256) void k_prologue(KArgs a)
{
    __shared__ __align__(16) char smem[13440];
    int b = blockIdx.x, tid = threadIdx.x;
    if (b < 960) phase_pack(a, b * 256 + tid, 960 * 256);
    else if (b < 1088) phase_init_s(a, smem, b - 960, tid);
    else {
        int base = (b - 1088) * 1024;
#pragma unroll
        for (int q = 0; q < 4; q++) atomicAdd(&a.cnt[a.ii[base + q * 256 + tid]], 1);
    }
}
__global__ __launch_bounds__(256) void k_prefix(KArgs a)
{
    __shared__ int part[256];
    int tid = threadIdx.x;
    int loc[8], sum = 0;
#pragma unroll
    for (int q = 0; q < 8; q++) { loc[q] = a.cnt[tid * 8 + q]; sum += loc[q]; }
    part[tid] = sum;
    __syncthreads();
    if (tid == 0) { int r = 0; for (int i = 0; i < 256; i++) { int v = part[i]; part[i] = r; r += v; } }
    __syncthreads();
    int r = part[tid];
#pragma unroll
    for (int q = 0; q < 8; q++) { a.rowpos[tid * 8 + q] = r; a.rowstart[tid * 8 + q] = r; r += loc[q]; }
}
__global__ void k_perm(KArgs a)
{
    int k = blockIdx.x * 256 + threadIdx.x;
    int iv = a.ii[k];
    int p = atomicAdd(&a.rowpos[iv], 1);
    a.invp[k] = p;
    a.i_s[p] = iv;
    a.j_s[p] = a.jj[k];
}
// init_e (blocks 0..1023) + proj0 (blocks 1024..1151) — independent work, NO intra-kernel sync.
__global__ __launch_bounds__(256) void k_initE(KArgs a)
{
    __shared__ __align__(16) char smem[15360];
    int bid = blockIdx.x, tid = threadIdx.x;
    if (bid < 1024) {
        phase_init_e(a, smem, bid, tid);
    } else {
        float s_reg[2][4];
        phase_node2(a, smem, bid - 1024, tid, false, false, false, false,
                    nullptr, nullptr, a.Wproj, s_reg, nullptr, 0);
    }
}

// fused layer: em(l) on blocks 0..1023 signals per-tile flags; node(l+1) on blocks 1024..1151
// consumes them (fine-grained) -> node latency hides under em tail. 1152 <= 1280 capacity.
__global__ __launch_bounds__(256, 5) void k_layer(KArgs a, int gen, int de, int dm,
        const short* We3p, const float* bedge_l, const short* W3mp, const float* bmsg_l,
        const short* Wpn_l, const float* bnode_l, const short* Wproj_slot, int dopost)
{
    __shared__ __align__(16) char smem[28160];
    int bid = blockIdx.x, tid = threadIdx.x;
    if (bid < 1024) {
        float e_reg[2][4];
        phase_em2(a, smem, bid, tid, de != 0, dm != 0, true, de != 0,
                  We3p, bedge_l, W3mp, bmsg_l, e_reg, a.eflag, gen);
    } else {
        float s_reg[2][4];
        phase_node2(a, smem, bid - 1024, tid, true, dopost != 0, true, true,
                    Wpn_l, bnode_l, Wproj_slot, s_reg, a.eflag, gen);
    }
}

// ---------------- fallback multi-kernel pieces -------------------------------------------------
__global__ __launch_bounds__(256) void k_init_e(KArgs a)
{
    __shared__ __align__(16) char smem[15360];
    phase_init_e(a, smem, blockIdx.x, threadIdx.x);
}
__global__ __launch_bounds__(256) void k_node_proj(KArgs a, int donode, int dopost,
                                                   const short* Wpn_l, const float* bnode_l,
                                                   const short* Wproj_slot)
{
    __shared__ __align__(16) char smem[12800];
    float s_reg[2][4];
    phase_node2(a, smem, blockIdx.x, threadIdx.x, donode != 0, dopost != 0,
                donode != 0, donode != 0, Wpn_l, bnode_l, Wproj_slot, s_reg, nullptr, 0);
}
__global__ __launch_bounds__(256) void k_em(KArgs a, int de, int dm, const short* We3p,
                                            const float* bedge_l, const short* W3mp, const float* bmsg_l)
{
    __shared__ __align__(16) char smem[28160];
    float e_reg[2][4];
    phase_em2(a, smem, blockIdx.x, threadIdx.x, de != 0, dm != 0, true, de != 0,
              We3p, bedge_l, W3mp, bmsg_l, e_reg, nullptr, 0);
}
__global__ __launch_bounds__(256) void k_post_edge(KArgs a)
{
    __shared__ __align__(16) char smem[23040];
    phase_post_edge(a, smem, blockIdx.x, threadIdx.x);
}

extern "C" void kernel_launch(void* const* d_in, const int* in_sizes, int n_in,
                              void* d_out, int out_size, void* d_ws, size_t ws_size,
                              hipStream_t stream) {
    KArgs a;
    a.x      = (const float*)d_in[0];
    a.t      = (const float*)d_in[1];
    a.z      = (const float*)d_in[2];
    const int* eidx = (const int*)d_in[3];
    a.jj     = eidx;        // edge_index[0] = j
    a.ii     = eidx + NE;   // edge_index[1] = i
    a.ea     = (const float*)d_in[4];
    a.batch  = (const int*)d_in[5];
    a.beg    = (const int*)d_in[6];
    a.Wt_a   = (const float*)d_in[7];
    a.bt_a   = (const float*)d_in[8];
    a.Wt_b   = (const float*)d_in[9];
    a.bt_b   = (const float*)d_in[10];
    a.W_atom = (const float*)d_in[11];
    a.b_atom = (const float*)d_in[12];
    a.W_bond = (const float*)d_in[13];
    a.b_bond = (const float*)d_in[14];
    a.W_lat  = (const float*)d_in[15];
    a.b_lat  = (const float*)d_in[16];
    a.W_at   = (const float*)d_in[17];
    a.b_at   = (const float*)d_in[18];
    a.W_bt   = (const float*)d_in[19];
    a.b_bt   = (const float*)d_in[20];
    a.Wmsg   = (const float*)d_in[21];
    a.bmsg   = (const float*)d_in[22];
    a.Wnode  = (const float*)d_in[23];
    a.bnode  = (const float*)d_in[24];
    a.Wedge  = (const float*)d_in[25];
    a.bedge  = (const float*)d_in[26];
    a.Wsh    = (const float*)d_in[27];
    a.bsh    = (const float*)d_in[28];
    a.Wbm    = (const float*)d_in[29];
    a.bbm    = (const float*)d_in[30];
    a.Wbl    = (const float*)d_in[31];
    a.bbl    = (const float*)d_in[32];
    a.Wal    = (const float*)d_in[33];
    a.bal    = (const float*)d_in[34];

    a.s        = (float*)d_ws;
    a.e        = a.s + (size_t)NN * CIN;
    a.agg      = a.e + (size_t)NE * CED;             // [NN][4][CIN] f32 (4 MB)
    a.cnt      = (int*)(a.agg + (size_t)NN * 4 * CIN);
    a.pflag    = a.cnt + NN;
    a.eflag    = a.pflag + 256;
    a.rowpos   = a.eflag + 1024;
    a.rowstart = a.rowpos + NN;
    a.invp     = a.rowstart + NN;
    a.i_s      = a.invp + NE;
    a.j_s      = a.i_s + NE;
    a.s2       = (short*)(a.j_s + NE);               // bf16 arrays
    a.U        = a.s2 + (size_t)NN * CIN;
    a.V        = a.U + (size_t)NN * CIN;
    a.P        = a.V + (size_t)NN * CIN;
    a.Q        = a.P + (size_t)NN * CED;
    a.map      = (int*)(a.Q + (size_t)NN * CED);
    a.Wpn      = (short*)(a.map + (size_t)NN * NN);
    a.Wpsh     = a.Wpn + (size_t)NL * 8 * 8 * 64 * 8;
    a.Wpal     = a.Wpsh + (size_t)4 * 8 * 64 * 8;
    a.Wpbm     = a.Wpal + (size_t)4 * 5 * 64 * 8;
    a.Wproj    = a.Wpbm + (size_t)8 * 64 * 8;
    a.W3m      = a.Wproj + (size_t)6 * 4 * 20 * 64 * 8;
    a.We3      = a.W3m + (size_t)NL * 8 * 64 * 8;
    a.out      = (float*)d_out;

    // gate: k_layer's intra-kernel flags require 1152 co-resident blocks (5 blocks/CU)
    static int mode = -1;
    if (mode < 0) {
        int dev = 0;
        (void)hipGetDevice(&dev);
        hipDeviceProp_t props;
        int ncu = 0;
        if (hipGetDeviceProperties(&props, dev) == hipSuccess) ncu = props.multiProcessorCount;
        int m1 = 0;
        if (hipOccupancyMaxActiveBlocksPerMultiprocessor(&m1, k_layer, 256, 0) != hipSuccess) m1 = 0;
        mode = ((long)m1 * ncu >= 1152) ? 1 : 0;
    }

    hipMemsetAsync(a.map, 0xFF, (size_t)NN * NN * sizeof(int), stream);
    hipMemsetAsync(a.agg, 0,
                   (size_t)NN * 4 * CIN * sizeof(float) + (NN + 256 + 1024) * sizeof(int),
                   stream);   // agg + cnt + pflag + eflag

    k_prologue<<<1152, 256, 0, stream>>>(a);
    k_prefix<<<1, 256, 0, stream>>>(a);
    k_perm<<<NE / 256, 256, 0, stream>>>(a);
    k_initE<<<1152, 256, 0, stream>>>(a);           // init_e + proj0, no spinning

    if (mode) {
        // D0..D4: em(edge=k-1 if k>0, msg=k) + node(k), fine-grained flags inside
        for (int k = 0; k < NL; k++) {
            int de = (k > 0) ? 1 : 0;
            k_layer<<<1152, 256, 0, stream>>>(a, k + 1, de, 1,
                de ? a.We3 + (size_t)(k - 1) * 2 * 64 * 8 : a.We3,
                de ? a.bedge + (k - 1) * CED : a.bedge,
                a.W3m + (size_t)k * 8 * 64 * 8, a.bmsg + k * CIN,
                a.Wpn + (size_t)k * 8 * 8 * 64 * 8, a.bnode + k * CIN,
                a.Wproj + (size_t)(k + 1) * 4 * 20 * 64 * 8, (k == NL - 1) ? 1 : 0);
        }
        // D5: final edge update only (writes e for post)
        k_layer<<<1024, 256, 0, stream>>>(a, NL + 1, 1, 0,
            a.We3 + (size_t)(NL - 1) * 2 * 64 * 8, a.bedge + (NL - 1) * CED,
            a.W3m, a.bmsg, a.Wpn, a.bnode, a.Wproj, 0);
    } else {
        k_em<<<NE / 64, 256, 0, stream>>>(a, 0, 1, nullptr, nullptr, a.W3m, a.bmsg);
        for (int l = 0; l < NL; l++) {
            int dopost = (l == NL - 1) ? 1 : 0;
            k_node_proj<<<NN / 16, 256, 0, stream>>>(a, 1, dopost,
                a.Wpn + (size_t)l * 8 * 8 * 64 * 8, a.bnode + l * CIN,
                a.Wproj + (size_t)(l + 1) * 4 * 20 * 64 * 8);
            int dm = (l < NL - 1) ? 1 : 0;
            k_em<<<NE / 64, 256, 0, stream>>>(a, 1, dm,
                a.We3 + (size_t)l * 2 * 64 * 8, a.bedge + l * CED,
                dm ? a.W3m + (size_t)(l + 1) * 8 * 64 * 8 : a.W3m,
                dm ? a.bmsg + (l + 1) * CIN : a.bmsg);
        }
    }
    k_post_edge<<<NE / 64, 256, 0, stream>>>(a);
}